// Round 1
// baseline (754.162 us; speedup 1.0000x reference)
//
#include <hip/hip_runtime.h>
#include <math.h>

#define NB 4
#define NT 48
#define NV 32
#define ND 512
#define NH 8
#define NHD 64
#define NOD 16
#define NN 1536   // T*V
#define NBN 6144  // B*N

// ---------------------------------------------------------------------------
// C = A(Mx K) @ W(K x Ncol) + bias.  remap=1: scatter cols into [b][h][n][64].
// 64x64 tile, 256 threads, 4x4 per thread. A staged transposed [k][row] in LDS
// so fragment reads are contiguous (ds_read_b128).
// ---------------------------------------------------------------------------
__global__ __launch_bounds__(256) void gemm64(
    const float* __restrict__ A, const float* __restrict__ W,
    const float* __restrict__ bias, float* __restrict__ C,
    int K, int Ncol, int remap)
{
    __shared__ float As[16][68];
    __shared__ float Bs[16][68];
    const int tid = threadIdx.x;
    const int tx = tid & 15, ty = tid >> 4;
    const int n0 = blockIdx.x * 64;
    const int m0 = blockIdx.y * 64;
    const int arow = tid >> 2, ac4 = (tid & 3) << 2;
    const int brow = tid >> 4, bc4 = (tid & 15) << 2;
    float acc[4][4] = {};
    for (int kt = 0; kt < K; kt += 16) {
        float4 av = *(const float4*)(A + (size_t)(m0 + arow) * K + kt + ac4);
        float4 bv = *(const float4*)(W + (size_t)(kt + brow) * Ncol + n0 + bc4);
        As[ac4 + 0][arow] = av.x;
        As[ac4 + 1][arow] = av.y;
        As[ac4 + 2][arow] = av.z;
        As[ac4 + 3][arow] = av.w;
        *(float4*)&Bs[brow][bc4] = bv;
        __syncthreads();
        #pragma unroll
        for (int kk = 0; kk < 16; kk++) {
            float4 a = *(const float4*)&As[kk][ty << 2];
            float4 b = *(const float4*)&Bs[kk][tx << 2];
            float ar[4] = {a.x, a.y, a.z, a.w};
            float br[4] = {b.x, b.y, b.z, b.w};
            #pragma unroll
            for (int i = 0; i < 4; i++)
                #pragma unroll
                for (int j = 0; j < 4; j++)
                    acc[i][j] += ar[i] * br[j];
        }
        __syncthreads();
    }
    float4 bvv = *(const float4*)(bias + n0 + (tx << 2));
    float bb[4] = {bvv.x, bvv.y, bvv.z, bvv.w};
    #pragma unroll
    for (int i = 0; i < 4; i++) {
        int grow = m0 + (ty << 2) + i;
        float4 res;
        res.x = acc[i][0] + bb[0];
        res.y = acc[i][1] + bb[1];
        res.z = acc[i][2] + bb[2];
        res.w = acc[i][3] + bb[3];
        size_t idx;
        if (remap) {
            // col = n0 + tx*4 + j ; head = n0>>6 (n0 multiple of 64, Ncol=512)
            int bb2 = grow / NN, nn = grow % NN;
            idx = ((((size_t)bb2 * NH + (n0 >> 6)) * NN + nn) << 6) + (tx << 2);
        } else {
            idx = (size_t)grow * Ncol + n0 + (tx << 2);
        }
        *(float4*)&C[idx] = res;
    }
}

// ---------------------------------------------------------------------------
// oq/ok projections: K=2 GEMM, one thread per output element.
// Outputs laid out [b][h][n][16].
// ---------------------------------------------------------------------------
__global__ __launch_bounds__(256) void oqok_kernel(
    const float* __restrict__ obs,
    const float* __restrict__ Woq, const float* __restrict__ boq,
    const float* __restrict__ Wok, const float* __restrict__ bok,
    float* __restrict__ oqo, float* __restrict__ oko)
{
    int t = blockIdx.x * 256 + threadIdx.x;
    if (t >= NBN * 128) return;
    int c = t & 127, bn = t >> 7;
    float o0 = obs[bn * 2 + 0], o1 = obs[bn * 2 + 1];
    int b = bn / NN, n = bn % NN;
    int hh = c >> 4, od = c & 15;
    size_t idx = ((((size_t)b * NH + hh) * NN + n) << 4) + od;
    oqo[idx] = o0 * Woq[c] + o1 * Woq[128 + c] + boq[c];
    oko[idx] = o0 * Wok[c] + o1 * Wok[128 + c] + bok[c];
}

// ---------------------------------------------------------------------------
// Flash-style attention. Block = (q-tile of 64 rows) x (b*H).
// Loops over 48 K/V tiles of 32 rows with online softmax.
// Q/K staged transposed [k][row] for b128 fragment reads; P stored [m][n].
// Biases: var_bias[h] staged in LDS (n%32, m%32); time bias = 2 scalars/tile.
// LDS total: 60032 B.
// ---------------------------------------------------------------------------
__global__ __launch_bounds__(256) void attn_kernel(
    const float* __restrict__ q, const float* __restrict__ k,
    const float* __restrict__ v, const float* __restrict__ oq,
    const float* __restrict__ ok, const float* __restrict__ varb,
    const float* __restrict__ rtb, float* __restrict__ out)
{
    __shared__ float Qs[64][68];   // [kk][row]
    __shared__ float Ks[64][36];   // [kk][m]
    __shared__ float OQs[16][68];  // [kk][row]
    __shared__ float OKs[16][36];  // [kk][m]
    __shared__ float Vs[32][68];   // [m][d]
    __shared__ float Ps[32][68];   // [m][n]
    __shared__ float red[64][17];
    __shared__ float rowm[64], rowl[64], rowa[64];
    __shared__ float vbs[32][33];

    const int tid = threadIdx.x;
    const int tx = tid & 15, ty = tid >> 4;
    const int qt = blockIdx.x;       // 0..23
    const int bh = blockIdx.y;       // b*H + h
    const int b = bh >> 3, h = bh & 7;
    const int n0 = qt << 6;

    const float* qb  = q  + ((size_t)bh * NN + n0) * 64;
    const float* oqb = oq + ((size_t)bh * NN + n0) * 16;
    const float* kb  = k  + (size_t)bh * NN * 64;
    const float* vb  = v  + (size_t)bh * NN * 64;
    const float* okb = ok + (size_t)bh * NN * 16;
    const float* rtbh = rtb + h * 95;

    // stage Q (64x64) transposed
    #pragma unroll
    for (int i = 0; i < 4; i++) {
        int idx = tid + (i << 8);
        int r = idx >> 4, c4 = (idx & 15) << 2;
        float4 t4 = *(const float4*)(qb + r * 64 + c4);
        Qs[c4 + 0][r] = t4.x; Qs[c4 + 1][r] = t4.y;
        Qs[c4 + 2][r] = t4.z; Qs[c4 + 3][r] = t4.w;
    }
    // stage OQ (64x16) transposed
    {
        int r = tid >> 2, c4 = (tid & 3) << 2;
        float4 t4 = *(const float4*)(oqb + r * 16 + c4);
        OQs[c4 + 0][r] = t4.x; OQs[c4 + 1][r] = t4.y;
        OQs[c4 + 2][r] = t4.z; OQs[c4 + 3][r] = t4.w;
    }
    // stage variable_bias[h] (32x32)
    #pragma unroll
    for (int i = 0; i < 4; i++) {
        int idx = tid + (i << 8);
        vbs[idx >> 5][idx & 31] = varb[h * 1024 + idx];
    }
    if (tid < 64) { rowm[tid] = -1e30f; rowl[tid] = 0.0f; }
    float O[4][4] = {};

    for (int mt = 0; mt < 48; mt++) {
        __syncthreads();   // protect K/V/OK (and red) from previous iteration
        const int m0 = mt << 5;
        // stage K (transposed) and V (natural), 32x64 each
        #pragma unroll
        for (int i = 0; i < 2; i++) {
            int idx = tid + (i << 8);
            int r = idx >> 4, c4 = (idx & 15) << 2;
            float4 t4 = *(const float4*)(kb + (size_t)(m0 + r) * 64 + c4);
            Ks[c4 + 0][r] = t4.x; Ks[c4 + 1][r] = t4.y;
            Ks[c4 + 2][r] = t4.z; Ks[c4 + 3][r] = t4.w;
            float4 v4 = *(const float4*)(vb + (size_t)(m0 + r) * 64 + c4);
            *(float4*)&Vs[r][c4] = v4;
        }
        // stage OK (32x16) transposed
        if (tid < 128) {
            int r = tid >> 2, c4 = (tid & 3) << 2;
            float4 t4 = *(const float4*)(okb + (size_t)(m0 + r) * 16 + c4);
            OKs[c4 + 0][r] = t4.x; OKs[c4 + 1][r] = t4.y;
            OKs[c4 + 2][r] = t4.z; OKs[c4 + 3][r] = t4.w;
        }
        __syncthreads();

        // S tile: rows ty*4+i, cols tx*2+j
        float s[4][2] = {};
        #pragma unroll 16
        for (int kk = 0; kk < 64; kk++) {
            float4 a = *(const float4*)&Qs[kk][ty << 2];
            float2 kv = *(const float2*)&Ks[kk][tx << 1];
            s[0][0] += a.x * kv.x; s[0][1] += a.x * kv.y;
            s[1][0] += a.y * kv.x; s[1][1] += a.y * kv.y;
            s[2][0] += a.z * kv.x; s[2][1] += a.z * kv.y;
            s[3][0] += a.w * kv.x; s[3][1] += a.w * kv.y;
        }
        float so[4][2] = {};
        #pragma unroll
        for (int kk = 0; kk < 16; kk++) {
            float4 a = *(const float4*)&OQs[kk][ty << 2];
            float2 kv = *(const float2*)&OKs[kk][tx << 1];
            so[0][0] += a.x * kv.x; so[0][1] += a.x * kv.y;
            so[1][0] += a.y * kv.x; so[1][1] += a.y * kv.y;
            so[2][0] += a.z * kv.x; so[2][1] += a.z * kv.y;
            so[3][0] += a.w * kv.x; so[3][1] += a.w * kv.y;
        }
        // fold in scales + biases. t_n = 2*qt + (row>=32), t_m = mt.
        float tb_lo = rtbh[2 * qt - mt + 47];
        float tb_hi = rtbh[2 * qt - mt + 48];
        float tb = (ty < 8) ? tb_lo : tb_hi;
        #pragma unroll
        for (int i = 0; i < 4; i++) {
            int rr = ((ty << 2) + i) & 31;
            #pragma unroll
            for (int j = 0; j < 2; j++) {
                s[i][j] = s[i][j] * 0.125f + so[i][j] * 0.25f
                        + vbs[rr][(tx << 1) + j] + tb;
            }
        }
        // row-max partials over this tile
        #pragma unroll
        for (int i = 0; i < 4; i++)
            red[(ty << 2) + i][tx] = fmaxf(s[i][0], s[i][1]);
        __syncthreads();
        if (tid < 64) {
            float mx = red[tid][0];
            #pragma unroll
            for (int j = 1; j < 16; j++) mx = fmaxf(mx, red[tid][j]);
            float mo = rowm[tid];
            float mn = fmaxf(mo, mx);
            float a = __expf(mo - mn);
            rowm[tid] = mn;
            rowa[tid] = a;
            rowl[tid] *= a;
        }
        __syncthreads();
        // exponentiate, store P transposed, rescale O
        #pragma unroll
        for (int i = 0; i < 4; i++) {
            int rr = (ty << 2) + i;
            float mn = rowm[rr];
            float p0 = __expf(s[i][0] - mn);
            float p1 = __expf(s[i][1] - mn);
            Ps[(tx << 1) + 0][rr] = p0;
            Ps[(tx << 1) + 1][rr] = p1;
            red[rr][tx] = p0 + p1;
            float a = rowa[rr];
            #pragma unroll
            for (int j = 0; j < 4; j++) O[i][j] *= a;
        }
        __syncthreads();
        if (tid < 64) {
            float sm = red[tid][0];
            #pragma unroll
            for (int j = 1; j < 16; j++) sm += red[tid][j];
            rowl[tid] += sm;
        }
        // O += P @ V   (k = 32)
        #pragma unroll 8
        for (int kk = 0; kk < 32; kk++) {
            float4 pv = *(const float4*)&Ps[kk][ty << 2];
            float4 vv = *(const float4*)&Vs[kk][tx << 2];
            float pr[4] = {pv.x, pv.y, pv.z, pv.w};
            float vr[4] = {vv.x, vv.y, vv.z, vv.w};
            #pragma unroll
            for (int i = 0; i < 4; i++)
                #pragma unroll
                for (int j = 0; j < 4; j++)
                    O[i][j] += pr[i] * vr[j];
        }
    }
    __syncthreads();   // rowl final
    #pragma unroll
    for (int i = 0; i < 4; i++) {
        int rr = (ty << 2) + i;
        float inv = 1.0f / rowl[rr];
        float4 res;
        res.x = O[i][0] * inv; res.y = O[i][1] * inv;
        res.z = O[i][2] * inv; res.w = O[i][3] * inv;
        int n = n0 + rr;
        // attn output laid out [b][n][h*64+d] == (B,N,D) row-major
        *(float4*)&out[((size_t)b * NN + n) * ND + h * 64 + (tx << 2)] = res;
    }
}

extern "C" void kernel_launch(void* const* d_in, const int* in_sizes, int n_in,
                              void* d_out, int out_size, void* d_ws, size_t ws_size,
                              hipStream_t stream)
{
    const float* h_   = (const float*)d_in[0];
    const float* obs  = (const float*)d_in[1];
    const float* Wq   = (const float*)d_in[2];
    const float* bq   = (const float*)d_in[3];
    const float* Wk   = (const float*)d_in[4];
    const float* bk   = (const float*)d_in[5];
    const float* Wv   = (const float*)d_in[6];
    const float* bv   = (const float*)d_in[7];
    const float* Wo   = (const float*)d_in[8];
    const float* bo   = (const float*)d_in[9];
    const float* Woq  = (const float*)d_in[10];
    const float* boq  = (const float*)d_in[11];
    const float* Wok  = (const float*)d_in[12];
    const float* bok  = (const float*)d_in[13];
    const float* varb = (const float*)d_in[14];
    const float* rtb  = (const float*)d_in[15];
    float* out = (float*)d_out;

    float* ws = (float*)d_ws;
    float* q    = ws;                               // [B][H][N][64]
    float* k    = q  + (size_t)NBN * 512;
    float* v    = k  + (size_t)NBN * 512;
    float* oq   = v  + (size_t)NBN * 512;           // [B][H][N][16]
    float* ok   = oq + (size_t)NBN * 128;
    float* attn = ok + (size_t)NBN * 128;           // [B][N][D]

    dim3 blk(256);
    dim3 gg(8, 96);    // (Ncol/64, M/64)
    gemm64<<<gg, blk, 0, stream>>>(h_, Wq, bq, q, 512, 512, 1);
    gemm64<<<gg, blk, 0, stream>>>(h_, Wk, bk, k, 512, 512, 1);
    gemm64<<<gg, blk, 0, stream>>>(h_, Wv, bv, v, 512, 512, 1);
    oqok_kernel<<<dim3((NBN * 128 + 255) / 256), blk, 0, stream>>>(
        obs, Woq, boq, Wok, bok, oq, ok);
    attn_kernel<<<dim3(24, 32), blk, 0, stream>>>(q, k, v, oq, ok, varb, rtb, attn);
    gemm64<<<gg, blk, 0, stream>>>(attn, Wo, bo, out, 512, 512, 0);
}

// Round 2
// 339.805 us; speedup vs baseline: 2.2194x; 2.2194x over previous
//
#include <hip/hip_runtime.h>
#include <math.h>

typedef __bf16 bf16x8 __attribute__((ext_vector_type(8)));
typedef float f32x4 __attribute__((ext_vector_type(4)));

#define NB 4
#define NT 48
#define NV 32
#define ND 512
#define NH 8
#define NN 1536   // T*V
#define NBN 6144  // B*N
#define KQ 96     // padded q'/k' feature dim (64 content + 16 obs + 16 zero)

// ---------------------------------------------------------------------------
// h -> bf16 (same layout), 8 elems/thread
// ---------------------------------------------------------------------------
__global__ __launch_bounds__(256) void conv_h(const float* __restrict__ h,
                                              __bf16* __restrict__ o)
{
    int t = blockIdx.x * 256 + threadIdx.x;            // 393216 threads
    const float4* src = (const float4*)h + (size_t)t * 2;
    float4 a = src[0], b = src[1];
    __bf16 r[8] = {(__bf16)a.x, (__bf16)a.y, (__bf16)a.z, (__bf16)a.w,
                   (__bf16)b.x, (__bf16)b.y, (__bf16)b.z, (__bf16)b.w};
    *(uint4*)(o + (size_t)t * 8) = *(uint4*)r;
}

// ---------------------------------------------------------------------------
// Build WcatT[c][k] = {Wq|Wk|Wv}[k][c&511] (bf16), WoT[c][k] = Wo[k][c],
// biascat[c] = {bq|bk|bv}[c&511].
// ---------------------------------------------------------------------------
__global__ __launch_bounds__(256) void conv_w(
    const float* __restrict__ Wq, const float* __restrict__ Wk,
    const float* __restrict__ Wv, const float* __restrict__ Wo,
    const float* __restrict__ bq, const float* __restrict__ bk,
    const float* __restrict__ bv,
    __bf16* __restrict__ WcatT, __bf16* __restrict__ WoT,
    float* __restrict__ biascat)
{
    int t = blockIdx.x * 256 + threadIdx.x;            // 1048576 threads
    if (t < 786432) {
        int c = t >> 9, kk = t & 511;
        int p = c >> 9, f = c & 511;
        const float* W = (p == 0) ? Wq : ((p == 1) ? Wk : Wv);
        WcatT[t] = (__bf16)W[kk * 512 + f];
        if (kk == 0) {
            const float* bb = (p == 0) ? bq : ((p == 1) ? bk : bv);
            biascat[c] = bb[f];
        }
    } else {
        int u = t - 786432;
        int c = u >> 9, kk = u & 511;
        WoT[u] = (__bf16)Wo[kk * 512 + c];
    }
}

// ---------------------------------------------------------------------------
// oq/ok (K=2) into q'/k' cols 64..79 (scaled), zeros into cols 80..95.
// ---------------------------------------------------------------------------
__global__ __launch_bounds__(256) void oqok_pad(
    const float* __restrict__ obs,
    const float* __restrict__ Woq, const float* __restrict__ boq,
    const float* __restrict__ Wok, const float* __restrict__ bok,
    __bf16* __restrict__ qo, __bf16* __restrict__ ko)
{
    int t = blockIdx.x * 256 + threadIdx.x;            // 6144*8*32 threads
    int j = t & 31, hh = (t >> 5) & 7, bn = t >> 8;
    int b = bn / NN, n = bn % NN;
    size_t base = (((size_t)b * NH + hh) * NN + n) * KQ + 64 + j;
    if (j < 16) {
        float o0 = obs[bn * 2], o1 = obs[bn * 2 + 1];
        int f = hh * 16 + j;
        float oqv = o0 * Woq[f] + o1 * Woq[128 + f] + boq[f];
        float okv = o0 * Wok[f] + o1 * Wok[128 + f] + bok[f];
        qo[base] = (__bf16)(0.25f * oqv);
        ko[base] = (__bf16)okv;
    } else {
        qo[base] = (__bf16)0.0f;
        ko[base] = (__bf16)0.0f;
    }
}

// ---------------------------------------------------------------------------
// bf16 MFMA GEMM: C = A(M x 512) @ Bt^T + bias.  Bt is [Ncol][512] k-contig.
// 128x128 tile, 4 waves in 2x2, each wave 64x64 via 4x4 MFMA 16x16x32 tiles.
// mode 0: fp32 out [M][512] (out projection).  mode 1: QKV epilogue.
// ---------------------------------------------------------------------------
__global__ __launch_bounds__(256) void gemm_mfma(
    const __bf16* __restrict__ A, const __bf16* __restrict__ Bt,
    const float* __restrict__ bias, float* __restrict__ Cout,
    __bf16* __restrict__ qo, __bf16* __restrict__ ko, __bf16* __restrict__ vo,
    int mode)
{
    __shared__ __bf16 As[128][32];
    __shared__ __bf16 Bs[128][32];
    const int tid = threadIdx.x;
    const int w = tid >> 6, lane = tid & 63;
    const int quad = lane >> 4, l16 = lane & 15;
    const int wm = w >> 1, wn = w & 1;
    const int n0 = blockIdx.x * 128, m0 = blockIdx.y * 128;

    f32x4 zero4 = {0.f, 0.f, 0.f, 0.f};
    f32x4 acc[4][4];
    #pragma unroll
    for (int i = 0; i < 4; i++)
        #pragma unroll
        for (int j = 0; j < 4; j++) acc[i][j] = zero4;

    for (int kt = 0; kt < 512; kt += 32) {
        uint4 av[2], bv[2];
        #pragma unroll
        for (int i = 0; i < 2; i++) {
            int off = tid + i * 256;                   // chunk 0..511
            int m = off >> 2, k8 = off & 3;
            av[i] = *(const uint4*)(A  + (size_t)(m0 + m) * 512 + kt + k8 * 8);
            bv[i] = *(const uint4*)(Bt + (size_t)(n0 + m) * 512 + kt + k8 * 8);
        }
        __syncthreads();
        #pragma unroll
        for (int i = 0; i < 2; i++) {
            int off = tid + i * 256;
            int m = off >> 2, k8 = off & 3;
            *(uint4*)&As[m][k8 * 8] = av[i];
            *(uint4*)&Bs[m][k8 * 8] = bv[i];
        }
        __syncthreads();
        bf16x8 af[4], bf[4];
        #pragma unroll
        for (int mt = 0; mt < 4; mt++)
            af[mt] = *(const bf16x8*)&As[wm * 64 + mt * 16 + l16][quad * 8];
        #pragma unroll
        for (int nt = 0; nt < 4; nt++)
            bf[nt] = *(const bf16x8*)&Bs[wn * 64 + nt * 16 + l16][quad * 8];
        #pragma unroll
        for (int mt = 0; mt < 4; mt++)
            #pragma unroll
            for (int nt = 0; nt < 4; nt++)
                acc[mt][nt] = __builtin_amdgcn_mfma_f32_16x16x32_bf16(
                    af[mt], bf[nt], acc[mt][nt], 0, 0, 0);
    }

    #pragma unroll
    for (int mt = 0; mt < 4; mt++) {
        #pragma unroll
        for (int nt = 0; nt < 4; nt++) {
            int c = n0 + wn * 64 + nt * 16 + l16;
            float bia = bias[c];
            #pragma unroll
            for (int r = 0; r < 4; r++) {
                int row = m0 + wm * 64 + mt * 16 + quad * 4 + r;
                float val = acc[mt][nt][r] + bia;
                if (mode == 0) {
                    Cout[(size_t)row * 512 + c] = val;
                } else {
                    int p = c >> 9, f = c & 511, hh = f >> 6, d = f & 63;
                    int b = row / NN, nn = row % NN;
                    size_t bhn = ((size_t)b * NH + hh) * NN + nn;
                    if (p == 0)      qo[bhn * KQ + d] = (__bf16)(val * 0.125f);
                    else if (p == 1) ko[bhn * KQ + d] = (__bf16)val;
                    else             vo[bhn * 64 + d] = (__bf16)val;
                }
            }
        }
    }
}

// ---------------------------------------------------------------------------
// Flash attention, bf16 MFMA. Block = 256 thr (4 waves) x Q-tile 128 rows,
// KV tiles of 64. Wave w owns Q rows [w*32, w*32+32).
// S = q'.k' over K=96 (scales folded). Softmax rows live per-(quad,reg) with
// 16-lane shfl reductions. P -> LDS (A-layout) -> PV MFMA over K=64.
// ---------------------------------------------------------------------------
__global__ __launch_bounds__(256) void attn_mfma(
    const __bf16* __restrict__ qp, const __bf16* __restrict__ kp,
    const __bf16* __restrict__ vp, const float* __restrict__ varb,
    const float* __restrict__ rtb, __bf16* __restrict__ aout)
{
    __shared__ __bf16 Ks[64][104];   // [m][kdim]  pad 96->104
    __shared__ __bf16 Vt[64][72];    // [d][m]     pad 64->72
    __shared__ __bf16 Ps[128][72];   // [n][m]     pad 64->72
    __shared__ float  vbs[32][33];
    __shared__ float  rts[96];

    const int tid = threadIdx.x;
    const int w = tid >> 6, lane = tid & 63;
    const int quad = lane >> 4, l16 = lane & 15;
    const int qt = blockIdx.x, bh = blockIdx.y;
    const int b = bh >> 3, h = bh & 7;
    const int n0 = qt * 128;

    const __bf16* qb = qp + ((size_t)bh * NN + n0) * KQ;
    const __bf16* kb = kp + (size_t)bh * NN * KQ;
    const __bf16* vb = vp + (size_t)bh * NN * 64;

    for (int i = tid; i < 1024; i += 256) vbs[i >> 5][i & 31] = varb[h * 1024 + i];
    if (tid < 95) rts[tid] = rtb[h * 95 + tid];

    // Q fragments (A-layout), resident for the whole kernel
    bf16x8 aq[2][3];
    #pragma unroll
    for (int rbl = 0; rbl < 2; rbl++)
        #pragma unroll
        for (int ks = 0; ks < 3; ks++)
            aq[rbl][ks] = *(const bf16x8*)(qb + (size_t)(w * 32 + rbl * 16 + l16) * KQ
                                              + ks * 32 + quad * 8);

    f32x4 zero4 = {0.f, 0.f, 0.f, 0.f};
    f32x4 o[2][4];
    float m_r[2][4], l_r[2][4];
    #pragma unroll
    for (int i = 0; i < 2; i++)
        #pragma unroll
        for (int j = 0; j < 4; j++) {
            o[i][j] = zero4; m_r[i][j] = -1e30f; l_r[i][j] = 0.f;
        }

    const int tn = (n0 >> 5) + w;

    for (int mt = 0; mt < 24; mt++) {
        const int m0 = mt * 64;
        __syncthreads();   // previous iter's K/V reads complete
        // stage k' tile (64 x 96)
        #pragma unroll
        for (int i = 0; i < 3; i++) {
            int c = tid + i * 256;
            int row = c / 12, c8 = c % 12;
            uint4 t4 = *(const uint4*)(kb + (size_t)(m0 + row) * KQ + c8 * 8);
            *(uint4*)&Ks[row][c8 * 8] = t4;
        }
        // stage V transposed: Vt[d][m]
        {
            int d8 = tid >> 5, p = tid & 31;
            const __bf16* vr = vb + (size_t)(m0 + 2 * p) * 64 + d8 * 8;
            uint4 lo = *(const uint4*)vr;
            uint4 hi = *(const uint4*)(vr + 64);
            const unsigned short* lo16 = (const unsigned short*)&lo;
            const unsigned short* hi16 = (const unsigned short*)&hi;
            #pragma unroll
            for (int j = 0; j < 8; j++) {
                unsigned int pk = (unsigned int)lo16[j] | ((unsigned int)hi16[j] << 16);
                *(unsigned int*)&Vt[d8 * 8 + j][2 * p] = pk;
            }
        }
        __syncthreads();

        #pragma unroll
        for (int rbl = 0; rbl < 2; rbl++) {
            // ---- S tiles (K=96 -> 3 MFMA steps) ----
            f32x4 sc[4];
            #pragma unroll
            for (int ct = 0; ct < 4; ct++) {
                f32x4 d = zero4;
                #pragma unroll
                for (int ks = 0; ks < 3; ks++) {
                    bf16x8 bf = *(const bf16x8*)&Ks[ct * 16 + l16][ks * 32 + quad * 8];
                    d = __builtin_amdgcn_mfma_f32_16x16x32_bf16(aq[rbl][ks], bf, d, 0, 0, 0);
                }
                sc[ct] = d;
            }
            // ---- biases ----
            float sv[4][4];
            #pragma unroll
            for (int ct = 0; ct < 4; ct++) {
                int tm = mt * 2 + (ct >> 1);
                float tb = rts[tn - tm + 47];
                #pragma unroll
                for (int r = 0; r < 4; r++) {
                    float vbv = vbs[rbl * 16 + quad * 4 + r][(ct & 1) * 16 + l16];
                    sv[ct][r] = sc[ct][r] + tb + vbv;
                }
            }
            // ---- online softmax (row = quad*4+r, 16 lanes share a row) ----
            #pragma unroll
            for (int r = 0; r < 4; r++) {
                float mx = fmaxf(fmaxf(sv[0][r], sv[1][r]), fmaxf(sv[2][r], sv[3][r]));
                mx = fmaxf(mx, __shfl_xor(mx, 1));
                mx = fmaxf(mx, __shfl_xor(mx, 2));
                mx = fmaxf(mx, __shfl_xor(mx, 4));
                mx = fmaxf(mx, __shfl_xor(mx, 8));
                float mo = m_r[rbl][r];
                float mn = fmaxf(mo, mx);
                float alpha = __expf(mo - mn);
                float p0 = __expf(sv[0][r] - mn);
                float p1 = __expf(sv[1][r] - mn);
                float p2 = __expf(sv[2][r] - mn);
                float p3 = __expf(sv[3][r] - mn);
                float rs = p0 + p1 + p2 + p3;
                rs += __shfl_xor(rs, 1);
                rs += __shfl_xor(rs, 2);
                rs += __shfl_xor(rs, 4);
                rs += __shfl_xor(rs, 8);
                l_r[rbl][r] = l_r[rbl][r] * alpha + rs;
                m_r[rbl][r] = mn;
                int prow = w * 32 + rbl * 16 + quad * 4 + r;
                Ps[prow][0 * 16 + l16] = (__bf16)p0;
                Ps[prow][1 * 16 + l16] = (__bf16)p1;
                Ps[prow][2 * 16 + l16] = (__bf16)p2;
                Ps[prow][3 * 16 + l16] = (__bf16)p3;
                #pragma unroll
                for (int dt = 0; dt < 4; dt++) o[rbl][dt][r] *= alpha;
            }
            // ---- PV (K=64 -> 2 MFMA steps); P rows are wave-private ----
            #pragma unroll
            for (int ks = 0; ks < 2; ks++) {
                bf16x8 pf = *(const bf16x8*)&Ps[w * 32 + rbl * 16 + l16][ks * 32 + quad * 8];
                #pragma unroll
                for (int dt = 0; dt < 4; dt++) {
                    bf16x8 vf = *(const bf16x8*)&Vt[dt * 16 + l16][ks * 32 + quad * 8];
                    o[rbl][dt] = __builtin_amdgcn_mfma_f32_16x16x32_bf16(pf, vf, o[rbl][dt], 0, 0, 0);
                }
            }
        }
    }

    // epilogue: write bf16 attn-out [b][n][h*64+d]
    #pragma unroll
    for (int rbl = 0; rbl < 2; rbl++)
        #pragma unroll
        for (int r = 0; r < 4; r++) {
            float inv = 1.0f / l_r[rbl][r];
            int n = n0 + w * 32 + rbl * 16 + quad * 4 + r;
            size_t base = ((size_t)b * NN + n) * 512 + h * 64 + l16;
            #pragma unroll
            for (int dt = 0; dt < 4; dt++)
                aout[base + dt * 16] = (__bf16)(o[rbl][dt][r] * inv);
        }
}

extern "C" void kernel_launch(void* const* d_in, const int* in_sizes, int n_in,
                              void* d_out, int out_size, void* d_ws, size_t ws_size,
                              hipStream_t stream)
{
    const float* h_   = (const float*)d_in[0];
    const float* obs  = (const float*)d_in[1];
    const float* Wq   = (const float*)d_in[2];
    const float* bq   = (const float*)d_in[3];
    const float* Wk   = (const float*)d_in[4];
    const float* bk   = (const float*)d_in[5];
    const float* Wv   = (const float*)d_in[6];
    const float* bv   = (const float*)d_in[7];
    const float* Wo   = (const float*)d_in[8];
    const float* bo   = (const float*)d_in[9];
    const float* Woq  = (const float*)d_in[10];
    const float* boq  = (const float*)d_in[11];
    const float* Wok  = (const float*)d_in[12];
    const float* bok  = (const float*)d_in[13];
    const float* varb = (const float*)d_in[14];
    const float* rtb  = (const float*)d_in[15];
    float* out = (float*)d_out;

    char* ws = (char*)d_ws;
    __bf16* qo      = (__bf16*)ws;                 ws += (size_t)32 * NN * KQ * 2;  // 9.44 MB
    __bf16* ko      = (__bf16*)ws;                 ws += (size_t)32 * NN * KQ * 2;
    __bf16* vo      = (__bf16*)ws;                 ws += (size_t)32 * NN * 64 * 2;  // 6.29 MB
    __bf16* h_bf    = (__bf16*)ws;                 ws += (size_t)NBN * 512 * 2;
    __bf16* attnout = (__bf16*)ws;                 ws += (size_t)NBN * 512 * 2;
    __bf16* WcatT   = (__bf16*)ws;                 ws += (size_t)1536 * 512 * 2;
    __bf16* WoT     = (__bf16*)ws;                 ws += (size_t)512 * 512 * 2;
    float*  biascat = (float*)ws;                  ws += 1536 * 4;

    conv_h<<<dim3(1536), dim3(256), 0, stream>>>(h_, h_bf);
    conv_w<<<dim3(4096), dim3(256), 0, stream>>>(Wq, Wk, Wv, Wo, bq, bk, bv,
                                                 WcatT, WoT, biascat);
    gemm_mfma<<<dim3(12, 48), dim3(256), 0, stream>>>(
        h_bf, WcatT, biascat, nullptr, qo, ko, vo, 1);
    oqok_pad<<<dim3(6144), dim3(256), 0, stream>>>(obs, Woq, boq, Wok, bok, qo, ko);
    attn_mfma<<<dim3(12, 32), dim3(256), 0, stream>>>(qo, ko, vo, varb, rtb, attnout);
    gemm_mfma<<<dim3(4, 48), dim3(256), 0, stream>>>(
        attnout, WoT, bo, out, nullptr, nullptr, nullptr, 0);
}

// Round 3
// 215.200 us; speedup vs baseline: 3.5045x; 1.5790x over previous
//
#include <hip/hip_runtime.h>
#include <math.h>

typedef __bf16 bf16x8 __attribute__((ext_vector_type(8)));
typedef float f32x4 __attribute__((ext_vector_type(4)));

#define NB 4
#define NT 48
#define NV 32
#define ND 512
#define NH 8
#define NN 1536   // T*V
#define NBN 6144  // B*N
#define KQ 96     // padded q'/k' feature dim (64 content + 16 obs + 16 zero)

#define GLOAD_LDS(g, l) \
    __builtin_amdgcn_global_load_lds( \
        (const __attribute__((address_space(1))) void*)(g), \
        (__attribute__((address_space(3))) void*)(l), 16, 0, 0)

// ---------------------------------------------------------------------------
// h -> bf16 (same layout), 8 elems/thread
// ---------------------------------------------------------------------------
__global__ __launch_bounds__(256) void conv_h(const float* __restrict__ h,
                                              __bf16* __restrict__ o)
{
    int t = blockIdx.x * 256 + threadIdx.x;            // 393216 threads
    const float4* src = (const float4*)h + (size_t)t * 2;
    float4 a = src[0], b = src[1];
    __bf16 r[8] = {(__bf16)a.x, (__bf16)a.y, (__bf16)a.z, (__bf16)a.w,
                   (__bf16)b.x, (__bf16)b.y, (__bf16)b.z, (__bf16)b.w};
    *(uint4*)(o + (size_t)t * 8) = *(uint4*)r;
}

// ---------------------------------------------------------------------------
// LDS-tiled transpose: WcatT[c][k] = {Wq|Wk|Wv}[k][c] bf16, WoT[c][k]=Wo[k][c].
// 256 blocks: p = bx>>6 (matrix), tile = bx&63 -> (k0, c0) 64x64.
// ---------------------------------------------------------------------------
__global__ __launch_bounds__(256) void conv_w(
    const float* __restrict__ Wq, const float* __restrict__ Wk,
    const float* __restrict__ Wv, const float* __restrict__ Wo,
    const float* __restrict__ bq, const float* __restrict__ bk,
    const float* __restrict__ bv,
    __bf16* __restrict__ WcatT, __bf16* __restrict__ WoT,
    float* __restrict__ biascat)
{
    __shared__ float ts[64][68];
    const int tid = threadIdx.x;
    const int bx = blockIdx.x;
    const int p = bx >> 6, tile = bx & 63;
    const int k0 = (tile >> 3) * 64, c0 = (tile & 7) * 64;
    const float* W = (p == 0) ? Wq : (p == 1) ? Wk : (p == 2) ? Wv : Wo;
    #pragma unroll
    for (int i = 0; i < 4; i++) {
        int r = (tid >> 4) + i * 16;
        float4 v = *(const float4*)(W + (size_t)(k0 + r) * 512 + c0 + (tid & 15) * 4);
        *(float4*)&ts[r][(tid & 15) * 4] = v;
    }
    __syncthreads();
    __bf16 tmp[16];
    #pragma unroll
    for (int j = 0; j < 16; j++)
        tmp[j] = (__bf16)ts[(tid & 3) * 16 + j][tid >> 2];
    int crow = c0 + (tid >> 2);
    __bf16* dst = (p < 3)
        ? WcatT + ((size_t)(p * 512 + crow)) * 512 + k0 + (tid & 3) * 16
        : WoT   + ((size_t)crow) * 512 + k0 + (tid & 3) * 16;
    *(uint4*)dst = *(uint4*)tmp;
    *(uint4*)(dst + 8) = *(uint4*)(tmp + 8);
    if (p < 3 && k0 == 0 && tid < 64) {
        const float* bb = (p == 0) ? bq : (p == 1) ? bk : bv;
        biascat[p * 512 + c0 + tid] = bb[c0 + tid];
    }
}

// ---------------------------------------------------------------------------
// oq/ok (K=2) into q'/k' cols 64..79 (scaled), zeros into cols 80..95.
// ---------------------------------------------------------------------------
__global__ __launch_bounds__(256) void oqok_pad(
    const float* __restrict__ obs,
    const float* __restrict__ Woq, const float* __restrict__ boq,
    const float* __restrict__ Wok, const float* __restrict__ bok,
    __bf16* __restrict__ qo, __bf16* __restrict__ ko)
{
    int t = blockIdx.x * 256 + threadIdx.x;            // 6144*8*32 threads
    int j = t & 31, hh = (t >> 5) & 7, bn = t >> 8;
    int b = bn / NN, n = bn % NN;
    size_t base = (((size_t)b * NH + hh) * NN + n) * KQ + 64 + j;
    if (j < 16) {
        float o0 = obs[bn * 2], o1 = obs[bn * 2 + 1];
        int f = hh * 16 + j;
        float oqv = o0 * Woq[f] + o1 * Woq[128 + f] + boq[f];
        float okv = o0 * Wok[f] + o1 * Wok[128 + f] + bok[f];
        qo[base] = (__bf16)(0.25f * oqv);
        ko[base] = (__bf16)okv;
    } else {
        qo[base] = (__bf16)0.0f;
        ko[base] = (__bf16)0.0f;
    }
}

// ---------------------------------------------------------------------------
// bf16 MFMA GEMM (m97-style global_load_lds staging + XOR-swizzled LDS).
// C = A(M x 512) @ Bt^T + bias.  Bt is [Ncol][512] k-contiguous.
// TM x 128 tile. mode 0: fp32 out [M][512].  mode 1: QKV scatter epilogue.
// ---------------------------------------------------------------------------
template<int TM>
__global__ __launch_bounds__(256) void gemm_mfma(
    const __bf16* __restrict__ A, const __bf16* __restrict__ Bt,
    const float* __restrict__ bias, float* __restrict__ Cout,
    __bf16* __restrict__ qo, __bf16* __restrict__ ko, __bf16* __restrict__ vo,
    int mode)
{
    constexpr int MT = TM / 32;          // 16-row m-tiles per wave
    __shared__ __bf16 As[TM][32];
    __shared__ __bf16 Bs[128][32];
    const int tid = threadIdx.x;
    const int w = tid >> 6, lane = tid & 63;
    const int quad = lane >> 4, l16 = lane & 15;
    const int wm = w >> 1, wn = w & 1;
    const int n0 = blockIdx.x * 128, m0 = blockIdx.y * TM;

    // staging: thread -> LDS slot tid*16B = (row tid>>2, col-chunk tid&3);
    // stored col c holds global k-chunk c ^ ((row>>1)&3)  (bank swizzle)
    const int sm = tid >> 2;
    const int sk = ((tid & 3) ^ ((sm >> 1) & 3)) * 8;
    const __bf16* aptr = A  + (size_t)(m0 + sm) * 512 + sk;
    const __bf16* bptr = Bt + (size_t)(n0 + sm) * 512 + sk;
    __bf16* lA = (__bf16*)As + tid * 8;
    __bf16* lB = (__bf16*)Bs + tid * 8;

    f32x4 zero4 = {0.f, 0.f, 0.f, 0.f};
    f32x4 acc[MT][4];
    #pragma unroll
    for (int i = 0; i < MT; i++)
        #pragma unroll
        for (int j = 0; j < 4; j++) acc[i][j] = zero4;

    for (int kt = 0; kt < 512; kt += 32) {
        __syncthreads();
        GLOAD_LDS(aptr + kt, lA);
        if (TM == 128) GLOAD_LDS(aptr + 64 * 512 + kt, lA + 2048);
        GLOAD_LDS(bptr + kt, lB);
        GLOAD_LDS(bptr + 64 * 512 + kt, lB + 2048);
        __syncthreads();
        bf16x8 af[MT], bfr[4];
        #pragma unroll
        for (int mt = 0; mt < MT; mt++) {
            int rr = wm * (TM / 2) + mt * 16 + l16;
            af[mt] = *(const bf16x8*)&As[rr][(quad ^ ((rr >> 1) & 3)) * 8];
        }
        #pragma unroll
        for (int nt = 0; nt < 4; nt++) {
            int rr = wn * 64 + nt * 16 + l16;
            bfr[nt] = *(const bf16x8*)&Bs[rr][(quad ^ ((rr >> 1) & 3)) * 8];
        }
        #pragma unroll
        for (int mt = 0; mt < MT; mt++)
            #pragma unroll
            for (int nt = 0; nt < 4; nt++)
                acc[mt][nt] = __builtin_amdgcn_mfma_f32_16x16x32_bf16(
                    af[mt], bfr[nt], acc[mt][nt], 0, 0, 0);
    }

    #pragma unroll
    for (int mt = 0; mt < MT; mt++) {
        #pragma unroll
        for (int nt = 0; nt < 4; nt++) {
            int c = n0 + wn * 64 + nt * 16 + l16;
            float bia = bias[c];
            #pragma unroll
            for (int r = 0; r < 4; r++) {
                int row = m0 + wm * (TM / 2) + mt * 16 + quad * 4 + r;
                float val = acc[mt][nt][r] + bia;
                if (mode == 0) {
                    Cout[(size_t)row * 512 + c] = val;
                } else {
                    int p = c >> 9, f = c & 511, hh = f >> 6, d = f & 63;
                    int b = row / NN, nn = row % NN;
                    size_t bhn = ((size_t)b * NH + hh) * NN + nn;
                    if (p == 0)      qo[bhn * KQ + d] = (__bf16)(val * 0.125f);
                    else if (p == 1) ko[bhn * KQ + d] = (__bf16)val;
                    else             vo[bhn * 64 + d] = (__bf16)val;
                }
            }
        }
    }
}

// ---------------------------------------------------------------------------
// Flash attention, bf16 MFMA, no-max softmax (scores bounded), reg-prefetch
// pipeline. Block = 4 waves x 16 Q-rows each (Q-tile 64), KV tiles of 64.
// Grid 24 x 32 = 768 blocks (3/CU co-resident). LDS ~32 KB.
// ---------------------------------------------------------------------------
__global__ __launch_bounds__(256, 4) void attn_mfma(
    const __bf16* __restrict__ qp, const __bf16* __restrict__ kp,
    const __bf16* __restrict__ vp, const float* __restrict__ varb,
    const float* __restrict__ rtb, __bf16* __restrict__ aout)
{
    __shared__ __bf16 Ks[64][104];   // [m][kdim] pad 96->104
    __shared__ __bf16 Vt[64][72];    // [d][m]    pad 64->72
    __shared__ __bf16 Ps[64][72];    // [n][m]    pad 64->72 (wave-private rows)
    __shared__ float  rts[96];

    const int tid = threadIdx.x;
    const int w = tid >> 6, lane = tid & 63;
    const int quad = lane >> 4, l16 = lane & 15;
    const int qt = blockIdx.x, bh = blockIdx.y;
    const int b = bh >> 3, h = bh & 7;
    const int n0 = qt * 64;

    const __bf16* qb = qp + ((size_t)bh * NN + n0) * KQ;
    const __bf16* kb = kp + (size_t)bh * NN * KQ;
    const __bf16* vb = vp + (size_t)bh * NN * 64;

    if (tid < 95) rts[tid] = rtb[h * 95 + tid];

    // Q fragments: wave w owns rows w*16..w*16+15
    bf16x8 aq[3];
    #pragma unroll
    for (int ks = 0; ks < 3; ks++)
        aq[ks] = *(const bf16x8*)(qb + (size_t)(w * 16 + l16) * KQ + ks * 32 + quad * 8);

    // var-bias in registers: row (n mod 32), cols l16 and l16+16
    float vb0[4], vb1[4];
    #pragma unroll
    for (int r = 0; r < 4; r++) {
        int rm = (w * 16 + quad * 4 + r) & 31;
        vb0[r] = varb[h * 1024 + rm * 32 + l16];
        vb1[r] = varb[h * 1024 + rm * 32 + 16 + l16];
    }
    const int tn = 2 * qt + (w >> 1);    // shared by all rows of this wave

    f32x4 zero4 = {0.f, 0.f, 0.f, 0.f};
    f32x4 o[4];
    float lpart[4];
    #pragma unroll
    for (int i = 0; i < 4; i++) { o[i] = zero4; lpart[i] = 0.f; }

    // staging maps
    const int kr0 = tid / 12,         kc0 = (tid % 12) * 8;
    const int kr1 = (tid + 256) / 12, kc1 = ((tid + 256) % 12) * 8;
    const int kr2 = (tid + 512) / 12, kc2 = ((tid + 512) % 12) * 8;
    const int vp2 = tid & 31, vd8 = tid >> 5;

    uint4 kreg[3], vreg[2];
    // prefetch tile 0
    kreg[0] = *(const uint4*)(kb + (size_t)kr0 * KQ + kc0);
    kreg[1] = *(const uint4*)(kb + (size_t)kr1 * KQ + kc1);
    kreg[2] = *(const uint4*)(kb + (size_t)kr2 * KQ + kc2);
    vreg[0] = *(const uint4*)(vb + (size_t)(2 * vp2) * 64 + vd8 * 8);
    vreg[1] = *(const uint4*)(vb + (size_t)(2 * vp2 + 1) * 64 + vd8 * 8);
    {
        *(uint4*)&Ks[kr0][kc0] = kreg[0];
        *(uint4*)&Ks[kr1][kc1] = kreg[1];
        *(uint4*)&Ks[kr2][kc2] = kreg[2];
        const unsigned short* lo = (const unsigned short*)&vreg[0];
        const unsigned short* hi = (const unsigned short*)&vreg[1];
        #pragma unroll
        for (int j = 0; j < 8; j++) {
            unsigned int pk = (unsigned int)lo[j] | ((unsigned int)hi[j] << 16);
            *(unsigned int*)&Vt[vd8 * 8 + j][2 * vp2] = pk;
        }
    }
    __syncthreads();

    for (int mt = 0; mt < 24; mt++) {
        // issue next tile's global loads (in flight during compute)
        if (mt < 23) {
            const __bf16* kbn = kb + (size_t)(mt + 1) * 64 * KQ;
            const __bf16* vbn = vb + (size_t)(mt + 1) * 64 * 64;
            kreg[0] = *(const uint4*)(kbn + (size_t)kr0 * KQ + kc0);
            kreg[1] = *(const uint4*)(kbn + (size_t)kr1 * KQ + kc1);
            kreg[2] = *(const uint4*)(kbn + (size_t)kr2 * KQ + kc2);
            vreg[0] = *(const uint4*)(vbn + (size_t)(2 * vp2) * 64 + vd8 * 8);
            vreg[1] = *(const uint4*)(vbn + (size_t)(2 * vp2 + 1) * 64 + vd8 * 8);
        }
        // ---- QK over K=96 ----
        f32x4 sc[4];
        #pragma unroll
        for (int ct = 0; ct < 4; ct++) {
            f32x4 d = zero4;
            #pragma unroll
            for (int ks = 0; ks < 3; ks++) {
                bf16x8 bf = *(const bf16x8*)&Ks[ct * 16 + l16][ks * 32 + quad * 8];
                d = __builtin_amdgcn_mfma_f32_16x16x32_bf16(aq[ks], bf, d, 0, 0, 0);
            }
            sc[ct] = d;
        }
        // ---- biases + exp (no max subtraction: scores bounded) ----
        float tb0 = rts[tn - 2 * mt + 47];
        float tb1 = rts[tn - 2 * mt + 46];
        #pragma unroll
        for (int ct = 0; ct < 4; ct++) {
            float tb = (ct & 2) ? tb1 : tb0;
            #pragma unroll
            for (int r = 0; r < 4; r++) {
                float s = sc[ct][r] + tb + ((ct & 1) ? vb1[r] : vb0[r]);
                float p = __expf(s);
                lpart[r] += p;
                Ps[w * 16 + quad * 4 + r][ct * 16 + l16] = (__bf16)p;
            }
        }
        // ---- PV (P rows wave-private: no barrier needed) ----
        #pragma unroll
        for (int ks = 0; ks < 2; ks++) {
            bf16x8 pf = *(const bf16x8*)&Ps[w * 16 + l16][ks * 32 + quad * 8];
            #pragma unroll
            for (int dt = 0; dt < 4; dt++) {
                bf16x8 vf = *(const bf16x8*)&Vt[dt * 16 + l16][ks * 32 + quad * 8];
                o[dt] = __builtin_amdgcn_mfma_f32_16x16x32_bf16(pf, vf, o[dt], 0, 0, 0);
            }
        }
        __syncthreads();   // everyone done reading Ks/Vt
        if (mt < 23) {
            *(uint4*)&Ks[kr0][kc0] = kreg[0];
            *(uint4*)&Ks[kr1][kc1] = kreg[1];
            *(uint4*)&Ks[kr2][kc2] = kreg[2];
            const unsigned short* lo = (const unsigned short*)&vreg[0];
            const unsigned short* hi = (const unsigned short*)&vreg[1];
            #pragma unroll
            for (int j = 0; j < 8; j++) {
                unsigned int pk = (unsigned int)lo[j] | ((unsigned int)hi[j] << 16);
                *(unsigned int*)&Vt[vd8 * 8 + j][2 * vp2] = pk;
            }
        }
        __syncthreads();
    }

    // final l reduction (once) + epilogue
    #pragma unroll
    for (int r = 0; r < 4; r++) {
        float l = lpart[r];
        l += __shfl_xor(l, 1);
        l += __shfl_xor(l, 2);
        l += __shfl_xor(l, 4);
        l += __shfl_xor(l, 8);
        float inv = 1.0f / l;
        int n = n0 + w * 16 + quad * 4 + r;
        size_t base = ((size_t)b * NN + n) * 512 + h * 64 + l16;
        #pragma unroll
        for (int dt = 0; dt < 4; dt++)
            aout[base + dt * 16] = (__bf16)(o[dt][r] * inv);
    }
}

extern "C" void kernel_launch(void* const* d_in, const int* in_sizes, int n_in,
                              void* d_out, int out_size, void* d_ws, size_t ws_size,
                              hipStream_t stream)
{
    const float* h_   = (const float*)d_in[0];
    const float* obs  = (const float*)d_in[1];
    const float* Wq   = (const float*)d_in[2];
    const float* bq   = (const float*)d_in[3];
    const float* Wk   = (const float*)d_in[4];
    const float* bk   = (const float*)d_in[5];
    const float* Wv   = (const float*)d_in[6];
    const float* bv   = (const float*)d_in[7];
    const float* Wo   = (const float*)d_in[8];
    const float* bo   = (const float*)d_in[9];
    const float* Woq  = (const float*)d_in[10];
    const float* boq  = (const float*)d_in[11];
    const float* Wok  = (const float*)d_in[12];
    const float* bok  = (const float*)d_in[13];
    const float* varb = (const float*)d_in[14];
    const float* rtb  = (const float*)d_in[15];
    float* out = (float*)d_out;

    char* ws = (char*)d_ws;
    __bf16* qo      = (__bf16*)ws;                 ws += (size_t)32 * NN * KQ * 2;
    __bf16* ko      = (__bf16*)ws;                 ws += (size_t)32 * NN * KQ * 2;
    __bf16* vo      = (__bf16*)ws;                 ws += (size_t)32 * NN * 64 * 2;
    __bf16* h_bf    = (__bf16*)ws;                 ws += (size_t)NBN * 512 * 2;
    __bf16* attnout = (__bf16*)ws;                 ws += (size_t)NBN * 512 * 2;
    __bf16* WcatT   = (__bf16*)ws;                 ws += (size_t)1536 * 512 * 2;
    __bf16* WoT     = (__bf16*)ws;                 ws += (size_t)512 * 512 * 2;
    float*  biascat = (float*)ws;                  ws += 1536 * 4;

    conv_h<<<dim3(1536), dim3(256), 0, stream>>>(h_, h_bf);
    conv_w<<<dim3(256), dim3(256), 0, stream>>>(Wq, Wk, Wv, Wo, bq, bk, bv,
                                                WcatT, WoT, biascat);
    gemm_mfma<128><<<dim3(12, 48), dim3(256), 0, stream>>>(
        h_bf, WcatT, biascat, nullptr, qo, ko, vo, 1);
    oqok_pad<<<dim3(6144), dim3(256), 0, stream>>>(obs, Woq, boq, Wok, bok, qo, ko);
    attn_mfma<<<dim3(24, 32), dim3(256), 0, stream>>>(qo, ko, vo, varb, rtb, attnout);
    gemm_mfma<64><<<dim3(4, 96), dim3(256), 0, stream>>>(
        attnout, WoT, bo, out, nullptr, nullptr, nullptr, 0);
}

// Round 6
// 187.761 us; speedup vs baseline: 4.0166x; 1.1461x over previous
//
#include <hip/hip_runtime.h>
#include <math.h>

typedef __bf16 bf16x8 __attribute__((ext_vector_type(8)));
typedef float f32x4 __attribute__((ext_vector_type(4)));

#define NB 4
#define NT 48
#define NV 32
#define ND 512
#define NH 8
#define NN 1536   // T*V
#define NBN 6144  // B*N

#define GLOAD_LDS(g, l) \
    __builtin_amdgcn_global_load_lds( \
        (const __attribute__((address_space(1))) void*)(g), \
        (__attribute__((address_space(3))) void*)(l), 16, 0, 0)

// ---------------------------------------------------------------------------
// h -> bf16 (same layout), 8 elems/thread
// ---------------------------------------------------------------------------
__global__ __launch_bounds__(256) void conv_h(const float* __restrict__ h,
                                              __bf16* __restrict__ o)
{
    int t = blockIdx.x * 256 + threadIdx.x;            // 393216 threads
    const float4* src = (const float4*)h + (size_t)t * 2;
    float4 a = src[0], b = src[1];
    __bf16 r[8] = {(__bf16)a.x, (__bf16)a.y, (__bf16)a.z, (__bf16)a.w,
                   (__bf16)b.x, (__bf16)b.y, (__bf16)b.z, (__bf16)b.w};
    *(uint4*)(o + (size_t)t * 8) = *(uint4*)r;
}

// ---------------------------------------------------------------------------
// LDS-tiled transpose of Wq/Wk/Wv/Wo (fold 0.125 into Wq and bq).
// WcatT[c][k] = {Wq*0.125|Wk|Wv}[k][c] bf16, WoT[c][k] = Wo[k][c].
// ---------------------------------------------------------------------------
__global__ __launch_bounds__(256) void conv_w(
    const float* __restrict__ Wq, const float* __restrict__ Wk,
    const float* __restrict__ Wv, const float* __restrict__ Wo,
    const float* __restrict__ bq, const float* __restrict__ bk,
    const float* __restrict__ bv,
    __bf16* __restrict__ WcatT, __bf16* __restrict__ WoT,
    float* __restrict__ biascat)
{
    __shared__ float ts[64][68];
    const int tid = threadIdx.x;
    const int bx = blockIdx.x;
    const int p = bx >> 6, tile = bx & 63;
    const int k0 = (tile >> 3) * 64, c0 = (tile & 7) * 64;
    const float* W = (p == 0) ? Wq : (p == 1) ? Wk : (p == 2) ? Wv : Wo;
    const float scale = (p == 0) ? 0.125f : 1.0f;
    #pragma unroll
    for (int i = 0; i < 4; i++) {
        int r = (tid >> 4) + i * 16;
        float4 v = *(const float4*)(W + (size_t)(k0 + r) * 512 + c0 + (tid & 15) * 4);
        *(float4*)&ts[r][(tid & 15) * 4] = v;
    }
    __syncthreads();
    __bf16 tmp[16];
    #pragma unroll
    for (int j = 0; j < 16; j++)
        tmp[j] = (__bf16)(ts[(tid & 3) * 16 + j][tid >> 2] * scale);
    int crow = c0 + (tid >> 2);
    __bf16* dst = (p < 3)
        ? WcatT + ((size_t)(p * 512 + crow)) * 512 + k0 + (tid & 3) * 16
        : WoT   + ((size_t)crow) * 512 + k0 + (tid & 3) * 16;
    *(uint4*)dst = *(uint4*)tmp;
    *(uint4*)(dst + 8) = *(uint4*)(tmp + 8);
    if (p < 3 && k0 == 0 && tid < 64) {
        const float* bb = (p == 0) ? bq : (p == 1) ? bk : bv;
        biascat[p * 512 + c0 + tid] = bb[c0 + tid] * scale;
    }
}

// ---------------------------------------------------------------------------
// kprep: kx[(b*8+h)*1536 + n][96] = [ k-content(64) | ok(16) | zeros(16) ].
// Single uniform array for attention K staging. Thread = (row, seg of 16).
// 32*1536*6/256 = 1152 blocks.
// ---------------------------------------------------------------------------
__global__ __launch_bounds__(256) void kprep(
    const __bf16* __restrict__ qkv, const float* __restrict__ obs,
    const float* __restrict__ Wok, const float* __restrict__ bok,
    __bf16* __restrict__ kx)
{
    int t = blockIdx.x * 256 + threadIdx.x;            // 294912 threads
    int row = t / 6, seg = t - row * 6;
    int b = row / 12288, rem = row - b * 12288;
    int h = rem >> 11 ? 0 : 0;                         // placeholder (computed below)
    h = rem / 1536;
    int n = rem - h * 1536;
    __bf16* dst = kx + (size_t)row * 96 + seg * 16;
    if (seg < 4) {
        const __bf16* src = qkv + ((size_t)(b * NN + n)) * 1536 + 512 + h * 64 + seg * 16;
        *(uint4*)dst       = *(const uint4*)src;
        *(uint4*)(dst + 8) = *(const uint4*)(src + 8);
    } else if (seg == 4) {
        float o0 = obs[(size_t)(b * NN + n) * 2];
        float o1 = obs[(size_t)(b * NN + n) * 2 + 1];
        int f = h * 16;
        __bf16 tmp[16];
        #pragma unroll
        for (int j = 0; j < 16; j++)
            tmp[j] = (__bf16)(o0 * Wok[f + j] + o1 * Wok[128 + f + j] + bok[f + j]);
        *(uint4*)dst       = *(uint4*)tmp;
        *(uint4*)(dst + 8) = *(uint4*)(tmp + 8);
    } else {
        uint4 z = {0, 0, 0, 0};
        *(uint4*)dst       = z;
        *(uint4*)(dst + 8) = z;
    }
}

// ---------------------------------------------------------------------------
// V transpose: vt[(b*8+h)*64 + d][n] = qkv[b*NN+n][1024 + h*64 + d].
// LDS-tiled, coalesced both sides. grid (24, 32).
// ---------------------------------------------------------------------------
__global__ __launch_bounds__(256) void vtrans(const __bf16* __restrict__ qkv,
                                              __bf16* __restrict__ vt)
{
    __shared__ __bf16 ts[64][72];
    const int tid = threadIdx.x;
    const int nt = blockIdx.x, bh = blockIdx.y;
    const int b = bh >> 3, h = bh & 7;
    const int n0 = nt * 64;
    const __bf16* src = qkv + ((size_t)(b * NN + n0 + (tid >> 2))) * 1536
                            + 1024 + h * 64 + (tid & 3) * 16;
    *(uint4*)&ts[tid >> 2][(tid & 3) * 16]     = *(const uint4*)src;
    *(uint4*)&ts[tid >> 2][(tid & 3) * 16 + 8] = *(const uint4*)(src + 8);
    __syncthreads();
    __bf16 tmp[16];
    #pragma unroll
    for (int j = 0; j < 16; j++)
        tmp[j] = ts[(tid & 3) * 16 + j][tid >> 2];
    __bf16* dst = vt + ((size_t)bh * 64 + (tid >> 2)) * 1536 + n0 + (tid & 3) * 16;
    *(uint4*)dst       = *(uint4*)tmp;
    *(uint4*)(dst + 8) = *(uint4*)(tmp + 8);
}

// ---------------------------------------------------------------------------
// bf16 MFMA GEMM (global_load_lds staging + XOR-swizzled LDS), natural
// epilogue. C = A(M x 512) @ Bt^T + bias, Bt is [Ncol][512] k-contiguous.
// BF16OUT: bf16 C (QKV), else fp32 C (out projection).
// ---------------------------------------------------------------------------
template<int TM, bool BF16OUT>
__global__ __launch_bounds__(256) void gemm_mfma(
    const __bf16* __restrict__ A, const __bf16* __restrict__ Bt,
    const float* __restrict__ bias, float* __restrict__ Cf,
    __bf16* __restrict__ Cbf, int Ncol)
{
    constexpr int MT = TM / 32;
    __shared__ __align__(16) __bf16 As[TM][32];
    __shared__ __align__(16) __bf16 Bs[128][32];
    const int tid = threadIdx.x;
    const int w = tid >> 6, lane = tid & 63;
    const int quad = lane >> 4, l16 = lane & 15;
    const int wm = w >> 1, wn = w & 1;
    const int n0 = blockIdx.x * 128, m0 = blockIdx.y * TM;

    const int sm = tid >> 2;
    const int sk = ((tid & 3) ^ ((sm >> 1) & 3)) * 8;
    const __bf16* aptr = A  + (size_t)(m0 + sm) * 512 + sk;
    const __bf16* bptr = Bt + (size_t)(n0 + sm) * 512 + sk;
    __bf16* lA = (__bf16*)As + tid * 8;
    __bf16* lB = (__bf16*)Bs + tid * 8;

    f32x4 zero4 = {0.f, 0.f, 0.f, 0.f};
    f32x4 acc[MT][4];
    #pragma unroll
    for (int i = 0; i < MT; i++)
        #pragma unroll
        for (int j = 0; j < 4; j++) acc[i][j] = zero4;

    for (int kt = 0; kt < 512; kt += 32) {
        __syncthreads();
        GLOAD_LDS(aptr + kt, lA);
        if (TM == 128) GLOAD_LDS(aptr + 64 * 512 + kt, lA + 2048);
        GLOAD_LDS(bptr + kt, lB);
        GLOAD_LDS(bptr + 64 * 512 + kt, lB + 2048);
        __syncthreads();
        bf16x8 af[MT], bfr[4];
        #pragma unroll
        for (int mt = 0; mt < MT; mt++) {
            int rr = wm * (TM / 2) + mt * 16 + l16;
            af[mt] = *(const bf16x8*)&As[rr][(quad ^ ((rr >> 1) & 3)) * 8];
        }
        #pragma unroll
        for (int nt = 0; nt < 4; nt++) {
            int rr = wn * 64 + nt * 16 + l16;
            bfr[nt] = *(const bf16x8*)&Bs[rr][(quad ^ ((rr >> 1) & 3)) * 8];
        }
        #pragma unroll
        for (int mt = 0; mt < MT; mt++)
            #pragma unroll
            for (int nt = 0; nt < 4; nt++)
                acc[mt][nt] = __builtin_amdgcn_mfma_f32_16x16x32_bf16(
                    af[mt], bfr[nt], acc[mt][nt], 0, 0, 0);
    }

    #pragma unroll
    for (int mt = 0; mt < MT; mt++) {
        #pragma unroll
        for (int nt = 0; nt < 4; nt++) {
            int c = n0 + wn * 64 + nt * 16 + l16;
            float bia = bias[c];
            #pragma unroll
            for (int r = 0; r < 4; r++) {
                int row = m0 + wm * (TM / 2) + mt * 16 + quad * 4 + r;
                float val = acc[mt][nt][r] + bia;
                if (BF16OUT) Cbf[(size_t)row * Ncol + c] = (__bf16)val;
                else         Cf[(size_t)row * Ncol + c] = val;
            }
        }
    }
}

// ---------------------------------------------------------------------------
// Flash attention, bf16 MFMA, no-max softmax, global_load_lds staging from
// a single uniform kx array (stride 96, +64 tail pad covers junk chunks).
// Block = 4 waves x 16 Q-rows (Q-tile 64), KV tiles of 64, grid 24x32.
// XOR chunk swizzle applied on GLOBAL addresses; LDS side lane-contiguous.
// LDS ~33 KB.
// ---------------------------------------------------------------------------
__global__ __launch_bounds__(256) void attn_mfma(
    const __bf16* __restrict__ qkv, const __bf16* __restrict__ kx,
    const __bf16* __restrict__ vt, const float* __restrict__ obs,
    const float* __restrict__ Woq, const float* __restrict__ boq,
    const float* __restrict__ varb, const float* __restrict__ rtb,
    __bf16* __restrict__ aout)
{
    __shared__ __align__(16) __bf16 Ks[64][128];  // [m][128]: 8 content,4 obs,4 junk
    __shared__ __align__(16) __bf16 Vs[64][64];   // [d][m] swizzled
    __shared__ __align__(16) __bf16 Ps[64][64];   // [n][m] swizzled
    __shared__ float rts[96];

    const int tid = threadIdx.x;
    const int w = tid >> 6, lane = tid & 63;
    const int quad = lane >> 4, l16 = lane & 15;
    const int qt = blockIdx.x, bh = blockIdx.y;
    const int b = bh >> 3, h = bh & 7;
    const int n0 = qt * 64;

    if (tid < 95) rts[tid] = rtb[h * 95 + tid];

    // Q fragments: wave w owns rows w*16..w*16+15
    const size_t qrow = (size_t)(b * NN + n0 + w * 16 + l16);
    bf16x8 aq[3];
    aq[0] = *(const bf16x8*)(qkv + qrow * 1536 + h * 64 + quad * 8);
    aq[1] = *(const bf16x8*)(qkv + qrow * 1536 + h * 64 + 32 + quad * 8);
    {   // inline oq: logical k 64..95 -> oq[0..15] then zeros; 0.25 folded
        uint4 a2u = {0u, 0u, 0u, 0u};
        if (quad < 2) {
            float o0 = obs[qrow * 2], o1 = obs[qrow * 2 + 1];
            int f = h * 16 + quad * 8;
            float4 w0a = *(const float4*)(Woq + f);
            float4 w0b = *(const float4*)(Woq + f + 4);
            float4 w1a = *(const float4*)(Woq + 128 + f);
            float4 w1b = *(const float4*)(Woq + 128 + f + 4);
            float4 ba  = *(const float4*)(boq + f);
            float4 bb2 = *(const float4*)(boq + f + 4);
            __bf16 tmp[8];
            tmp[0] = (__bf16)(0.25f * (o0 * w0a.x + o1 * w1a.x + ba.x));
            tmp[1] = (__bf16)(0.25f * (o0 * w0a.y + o1 * w1a.y + ba.y));
            tmp[2] = (__bf16)(0.25f * (o0 * w0a.z + o1 * w1a.z + ba.z));
            tmp[3] = (__bf16)(0.25f * (o0 * w0a.w + o1 * w1a.w + ba.w));
            tmp[4] = (__bf16)(0.25f * (o0 * w0b.x + o1 * w1b.x + bb2.x));
            tmp[5] = (__bf16)(0.25f * (o0 * w0b.y + o1 * w1b.y + bb2.y));
            tmp[6] = (__bf16)(0.25f * (o0 * w0b.z + o1 * w1b.z + bb2.z));
            tmp[7] = (__bf16)(0.25f * (o0 * w0b.w + o1 * w1b.w + bb2.w));
            a2u = *(uint4*)tmp;
        }
        aq[2] = *(bf16x8*)&a2u;
    }

    float vb0[4], vb1[4];
    #pragma unroll
    for (int r = 0; r < 4; r++) {
        int rm = (w * 16 + quad * 4 + r) & 31;
        vb0[r] = varb[h * 1024 + rm * 32 + l16];
        vb1[r] = varb[h * 1024 + rm * 32 + 16 + l16];
    }
    const int tn = 2 * qt + (w >> 1);

    // K staging: thread supplies phys chunk (tid&15) of rows (tid>>4)+16i;
    // logical chunk ck = (tid&15) ^ (row&7). Single uniform base array.
    const int ck = (tid & 15) ^ ((tid >> 4) & 7);
    const __bf16* kbase = kx + (size_t)bh * NN * 96 + ck * 8;
    // V staging: phys chunk (tid&7) of rows (tid>>3)+32i.
    const int cv = (tid & 7) ^ ((tid >> 3) & 7);
    const __bf16* vbase = vt + (size_t)bh * 64 * 1536 + cv * 8;

    f32x4 zero4 = {0.f, 0.f, 0.f, 0.f};
    f32x4 o[4];
    float lpart[4];
    #pragma unroll
    for (int i = 0; i < 4; i++) { o[i] = zero4; lpart[i] = 0.f; }

    char* ldsK = (char*)Ks;
    char* ldsV = (char*)Vs;

    for (int mt = 0; mt < 24; mt++) {
        const int m0 = mt * 64;
        __syncthreads();
        #pragma unroll
        for (int i = 0; i < 4; i++) {
            int row = i * 16 + (tid >> 4);
            GLOAD_LDS(kbase + (size_t)(m0 + row) * 96, ldsK + i * 4096 + tid * 16);
        }
        #pragma unroll
        for (int i = 0; i < 2; i++) {
            int row = i * 32 + (tid >> 3);
            GLOAD_LDS(vbase + (size_t)row * 1536 + m0, ldsV + i * 4096 + tid * 16);
        }
        __syncthreads();

        // ---- QK over K=96 ----
        f32x4 sc[4];
        #pragma unroll
        for (int ct = 0; ct < 4; ct++) {
            f32x4 d = zero4;
            int row = ct * 16 + l16;
            #pragma unroll
            for (int ks = 0; ks < 3; ks++) {
                bf16x8 bf = *(const bf16x8*)((const char*)Ks + row * 256
                                + (((ks * 4 + quad) ^ (row & 7)) * 16));
                d = __builtin_amdgcn_mfma_f32_16x16x32_bf16(aq[ks], bf, d, 0, 0, 0);
            }
            sc[ct] = d;
        }
        // ---- biases + exp (no max subtraction: scores bounded) ----
        float tb0 = rts[tn - 2 * mt + 47];
        float tb1 = rts[tn - 2 * mt + 46];
        #pragma unroll
        for (int ct = 0; ct < 4; ct++) {
            float tb = (ct & 2) ? tb1 : tb0;
            #pragma unroll
            for (int r = 0; r < 4; r++) {
                float s = sc[ct][r] + tb + ((ct & 1) ? vb1[r] : vb0[r]);
                float p = __expf(s);
                lpart[r] += p;
                int rowp = w * 16 + quad * 4 + r;
                int pc = ((ct * 2) + (l16 >> 3)) ^ (rowp & 7);
                Ps[rowp][pc * 8 + (l16 & 7)] = (__bf16)p;
            }
        }
        // ---- PV (P rows wave-private: no barrier) ----
        #pragma unroll
        for (int ks = 0; ks < 2; ks++) {
            int rowr = w * 16 + l16;
            bf16x8 pf = *(const bf16x8*)&Ps[rowr][((ks * 4 + quad) ^ (l16 & 7)) * 8];
            #pragma unroll
            for (int dt = 0; dt < 4; dt++) {
                int rw = dt * 16 + l16;
                bf16x8 vf = *(const bf16x8*)((const char*)Vs + rw * 128
                                + (((ks * 4 + quad) ^ (rw & 7)) * 16));
                o[dt] = __builtin_amdgcn_mfma_f32_16x16x32_bf16(pf, vf, o[dt], 0, 0, 0);
            }
        }
    }

    // final l reduction + epilogue: aout[b][n][h*64+d]
    #pragma unroll
    for (int r = 0; r < 4; r++) {
        float l = lpart[r];
        l += __shfl_xor(l, 1);
        l += __shfl_xor(l, 2);
        l += __shfl_xor(l, 4);
        l += __shfl_xor(l, 8);
        float inv = 1.0f / l;
        int n = n0 + w * 16 + quad * 4 + r;
        size_t base = ((size_t)b * NN + n) * 512 + h * 64 + l16;
        #pragma unroll
        for (int dt = 0; dt < 4; dt++)
            aout[base + dt * 16] = (__bf16)(o[dt][r] * inv);
    }
}

extern "C" void kernel_launch(void* const* d_in, const int* in_sizes, int n_in,
                              void* d_out, int out_size, void* d_ws, size_t ws_size,
                              hipStream_t stream)
{
    const float* h_   = (const float*)d_in[0];
    const float* obs  = (const float*)d_in[1];
    const float* Wq   = (const float*)d_in[2];
    const float* bq   = (const float*)d_in[3];
    const float* Wk   = (const float*)d_in[4];
    const float* bk   = (const float*)d_in[5];
    const float* Wv   = (const float*)d_in[6];
    const float* bv   = (const float*)d_in[7];
    const float* Wo   = (const float*)d_in[8];
    const float* bo   = (const float*)d_in[9];
    const float* Woq  = (const float*)d_in[10];
    const float* boq  = (const float*)d_in[11];
    const float* Wok  = (const float*)d_in[12];
    const float* bok  = (const float*)d_in[13];
    const float* varb = (const float*)d_in[14];
    const float* rtb  = (const float*)d_in[15];
    float* out = (float*)d_out;

    char* ws = (char*)d_ws;
    __bf16* h_bf    = (__bf16*)ws;                 ws += (size_t)NBN * 512 * 2;   // aliased by vt
    __bf16* qkv     = (__bf16*)ws;                 ws += (size_t)NBN * 1536 * 2;
    __bf16* kx      = (__bf16*)ws;                 ws += ((size_t)32 * NN * 96 + 64) * 2;
    __bf16* attnout = (__bf16*)ws;                 ws += (size_t)NBN * 512 * 2;
    __bf16* WcatT   = (__bf16*)ws;                 ws += (size_t)1536 * 512 * 2;
    __bf16* WoT     = (__bf16*)ws;                 ws += (size_t)512 * 512 * 2;
    float*  biascat = (float*)ws;                  ws += 1536 * 4;
    __bf16* vt      = h_bf;   // h_bf dead after QKV GEMM; vtrans runs after it

    conv_h<<<dim3(1536), dim3(256), 0, stream>>>(h_, h_bf);
    conv_w<<<dim3(256), dim3(256), 0, stream>>>(Wq, Wk, Wv, Wo, bq, bk, bv,
                                                WcatT, WoT, biascat);
    gemm_mfma<128, true><<<dim3(12, 48), dim3(256), 0, stream>>>(
        h_bf, WcatT, biascat, nullptr, qkv, 1536);
    kprep<<<dim3(1152), dim3(256), 0, stream>>>(qkv, obs, Wok, bok, kx);
    vtrans<<<dim3(24, 32), dim3(256), 0, stream>>>(qkv, vt);
    attn_mfma<<<dim3(24, 32), dim3(256), 0, stream>>>(qkv, kx, vt, obs, Woq, boq,
                                                      varb, rtb, attnout);
    gemm_mfma<64, false><<<dim3(4, 96), dim3(256), 0, stream>>>(
        attnout, WoT, bo, out, nullptr, 512);
}

// Round 9
// 187.480 us; speedup vs baseline: 4.0226x; 1.0015x over previous
//
#include <hip/hip_runtime.h>
#include <math.h>

typedef __bf16 bf16x8 __attribute__((ext_vector_type(8)));
typedef float f32x4 __attribute__((ext_vector_type(4)));

#define NB 4
#define NT 48
#define NV 32
#define ND 512
#define NH 8
#define NN 1536   // T*V
#define NBN 6144  // B*N
#define L2E 1.44269504f

#define GLOAD_LDS(g, l) \
    __builtin_amdgcn_global_load_lds( \
        (const __attribute__((address_space(1))) void*)(g), \
        (__attribute__((address_space(3))) void*)(l), 16, 0, 0)

// ---------------------------------------------------------------------------
// prep: fused conv_h (blocks 0..1535) + weight transpose (1536..1791) +
// kx obs/zero segments (1792..2175).  log2e folded into Wq/bq scale.
// ---------------------------------------------------------------------------
__global__ __launch_bounds__(256) void prep(
    const float* __restrict__ h, const float* __restrict__ obs,
    const float* __restrict__ Wq, const float* __restrict__ Wk,
    const float* __restrict__ Wv, const float* __restrict__ Wo,
    const float* __restrict__ bq, const float* __restrict__ bk,
    const float* __restrict__ bv,
    const float* __restrict__ Wok, const float* __restrict__ bok,
    __bf16* __restrict__ h_bf, __bf16* __restrict__ WcatT,
    __bf16* __restrict__ WoT, float* __restrict__ biascat,
    __bf16* __restrict__ kx)
{
    __shared__ float ts[64][68];
    const int tid = threadIdx.x;
    const int bx = blockIdx.x;
    if (bx < 1536) {
        // ---- h -> bf16, 8 elems/thread ----
        int t = bx * 256 + tid;
        const float4* src = (const float4*)h + (size_t)t * 2;
        float4 a = src[0], b = src[1];
        __bf16 r[8] = {(__bf16)a.x, (__bf16)a.y, (__bf16)a.z, (__bf16)a.w,
                       (__bf16)b.x, (__bf16)b.y, (__bf16)b.z, (__bf16)b.w};
        *(uint4*)(h_bf + (size_t)t * 8) = *(uint4*)r;
    } else if (bx < 1792) {
        // ---- LDS-tiled weight transpose ----
        int bw = bx - 1536;
        const int p = bw >> 6, tile = bw & 63;
        const int k0 = (tile >> 3) * 64, c0 = (tile & 7) * 64;
        const float* W = (p == 0) ? Wq : (p == 1) ? Wk : (p == 2) ? Wv : Wo;
        const float scale = (p == 0) ? 0.125f * L2E : 1.0f;
        #pragma unroll
        for (int i = 0; i < 4; i++) {
            int r = (tid >> 4) + i * 16;
            float4 v = *(const float4*)(W + (size_t)(k0 + r) * 512 + c0 + (tid & 15) * 4);
            *(float4*)&ts[r][(tid & 15) * 4] = v;
        }
        __syncthreads();
        __bf16 tmp[16];
        #pragma unroll
        for (int j = 0; j < 16; j++)
            tmp[j] = (__bf16)(ts[(tid & 3) * 16 + j][tid >> 2] * scale);
        int crow = c0 + (tid >> 2);
        __bf16* dst = (p < 3)
            ? WcatT + ((size_t)(p * 512 + crow)) * 512 + k0 + (tid & 3) * 16
            : WoT   + ((size_t)crow) * 512 + k0 + (tid & 3) * 16;
        *(uint4*)dst = *(uint4*)tmp;
        *(uint4*)(dst + 8) = *(uint4*)(tmp + 8);
        if (p < 3 && k0 == 0 && tid < 64) {
            const float* bb = (p == 0) ? bq : (p == 1) ? bk : bv;
            biascat[p * 512 + c0 + tid] = bb[c0 + tid] * scale;
        }
    } else {
        // ---- kx obs (cols 64..79) + zeros (80..95) ----
        int t = (bx - 1792) * 256 + tid;               // 0..98303
        int row = t >> 1, half = t & 1;                // row = bh*1536 + n
        __bf16* dst = kx + (size_t)row * 96 + 64 + half * 16;
        if (half == 0) {
            int bh = row / NN, n = row - bh * NN;
            int b = bh >> 3, hh = bh & 7;
            size_t bn = (size_t)b * NN + n;
            float o0 = obs[bn * 2], o1 = obs[bn * 2 + 1];
            int f = hh * 16;
            __bf16 tmp[16];
            #pragma unroll
            for (int j = 0; j < 16; j++)
                tmp[j] = (__bf16)(o0 * Wok[f + j] + o1 * Wok[128 + f + j] + bok[f + j]);
            *(uint4*)dst       = *(uint4*)tmp;
            *(uint4*)(dst + 8) = *(uint4*)(tmp + 8);
        } else {
            uint4 z = {0, 0, 0, 0};
            *(uint4*)dst       = z;
            *(uint4*)(dst + 8) = z;
        }
    }
}

// ---------------------------------------------------------------------------
// kvprep: kx k-content copy + V transpose, one block per (64-row n-tile, bh).
// kx[(bh*1536+n)][0..63] = qkv[b*NN+n][512+h*64 ..]; vt[bh*64+d][n] = V.
// grid (24, 32).
// ---------------------------------------------------------------------------
__global__ __launch_bounds__(256) void kvprep(const __bf16* __restrict__ qkv,
                                              __bf16* __restrict__ kx,
                                              __bf16* __restrict__ vt)
{
    __shared__ __bf16 ts[64][72];
    const int tid = threadIdx.x;
    const int nt = blockIdx.x, bh = blockIdx.y;
    const int b = bh >> 3, h = bh & 7;
    const int n0 = nt * 64;
    // k-content: row tid>>2, chunk tid&3
    {
        const __bf16* src = qkv + (size_t)(b * NN + n0 + (tid >> 2)) * 1536
                                + 512 + h * 64 + (tid & 3) * 16;
        __bf16* dst = kx + ((size_t)bh * NN + n0 + (tid >> 2)) * 96 + (tid & 3) * 16;
        *(uint4*)dst       = *(const uint4*)src;
        *(uint4*)(dst + 8) = *(const uint4*)(src + 8);
    }
    // V transpose
    const __bf16* src = qkv + ((size_t)(b * NN + n0 + (tid >> 2))) * 1536
                            + 1024 + h * 64 + (tid & 3) * 16;
    *(uint4*)&ts[tid >> 2][(tid & 3) * 16]     = *(const uint4*)src;
    *(uint4*)&ts[tid >> 2][(tid & 3) * 16 + 8] = *(const uint4*)(src + 8);
    __syncthreads();
    __bf16 tmp[16];
    #pragma unroll
    for (int j = 0; j < 16; j++)
        tmp[j] = ts[(tid & 3) * 16 + j][tid >> 2];
    __bf16* dst = vt + ((size_t)bh * 64 + (tid >> 2)) * 1536 + n0 + (tid & 3) * 16;
    *(uint4*)dst       = *(uint4*)tmp;
    *(uint4*)(dst + 8) = *(uint4*)(tmp + 8);
}

// ---------------------------------------------------------------------------
// bf16 MFMA GEMM (global_load_lds staging + XOR-swizzled LDS), natural
// epilogue. C = A(M x 512) @ Bt^T + bias, Bt is [Ncol][512] k-contiguous.
// ---------------------------------------------------------------------------
template<int TM, bool BF16OUT>
__global__ __launch_bounds__(256) void gemm_mfma(
    const __bf16* __restrict__ A, const __bf16* __restrict__ Bt,
    const float* __restrict__ bias, float* __restrict__ Cf,
    __bf16* __restrict__ Cbf, int Ncol)
{
    constexpr int MT = TM / 32;
    __shared__ __align__(16) __bf16 As[TM][32];
    __shared__ __align__(16) __bf16 Bs[128][32];
    const int tid = threadIdx.x;
    const int w = tid >> 6, lane = tid & 63;
    const int quad = lane >> 4, l16 = lane & 15;
    const int wm = w >> 1, wn = w & 1;
    const int n0 = blockIdx.x * 128, m0 = blockIdx.y * TM;

    const int sm = tid >> 2;
    const int sk = ((tid & 3) ^ ((sm >> 1) & 3)) * 8;
    const __bf16* aptr = A  + (size_t)(m0 + sm) * 512 + sk;
    const __bf16* bptr = Bt + (size_t)(n0 + sm) * 512 + sk;
    __bf16* lA = (__bf16*)As + tid * 8;
    __bf16* lB = (__bf16*)Bs + tid * 8;

    f32x4 zero4 = {0.f, 0.f, 0.f, 0.f};
    f32x4 acc[MT][4];
    #pragma unroll
    for (int i = 0; i < MT; i++)
        #pragma unroll
        for (int j = 0; j < 4; j++) acc[i][j] = zero4;

    for (int kt = 0; kt < 512; kt += 32) {
        __syncthreads();
        GLOAD_LDS(aptr + kt, lA);
        if (TM == 128) GLOAD_LDS(aptr + 64 * 512 + kt, lA + 2048);
        GLOAD_LDS(bptr + kt, lB);
        GLOAD_LDS(bptr + 64 * 512 + kt, lB + 2048);
        __syncthreads();
        bf16x8 af[MT], bfr[4];
        #pragma unroll
        for (int mt = 0; mt < MT; mt++) {
            int rr = wm * (TM / 2) + mt * 16 + l16;
            af[mt] = *(const bf16x8*)&As[rr][(quad ^ ((rr >> 1) & 3)) * 8];
        }
        #pragma unroll
        for (int nt = 0; nt < 4; nt++) {
            int rr = wn * 64 + nt * 16 + l16;
            bfr[nt] = *(const bf16x8*)&Bs[rr][(quad ^ ((rr >> 1) & 3)) * 8];
        }
        #pragma unroll
        for (int mt = 0; mt < MT; mt++)
            #pragma unroll
            for (int nt = 0; nt < 4; nt++)
                acc[mt][nt] = __builtin_amdgcn_mfma_f32_16x16x32_bf16(
                    af[mt], bfr[nt], acc[mt][nt], 0, 0, 0);
    }

    #pragma unroll
    for (int mt = 0; mt < MT; mt++) {
        #pragma unroll
        for (int nt = 0; nt < 4; nt++) {
            int c = n0 + wn * 64 + nt * 16 + l16;
            float bia = bias[c];
            #pragma unroll
            for (int r = 0; r < 4; r++) {
                int row = m0 + wm * (TM / 2) + mt * 16 + quad * 4 + r;
                float val = acc[mt][nt][r] + bia;
                if (BF16OUT) Cbf[(size_t)row * Ncol + c] = (__bf16)val;
                else         Cf[(size_t)row * Ncol + c] = val;
            }
        }
    }
}

// ---------------------------------------------------------------------------
// Flash attention, bf16 MFMA, no-max softmax (exp2, log2e pre-folded),
// single-buffered global_load_lds staging (R6-proven structure).
// Block = 4 waves x 16 Q-rows (Q-tile 64), KV tiles of 64, grid 24x32.
// XOR chunk swizzle on GLOBAL addresses; LDS side lane-contiguous.
// LDS ~33 KB.
// ---------------------------------------------------------------------------
__global__ __launch_bounds__(256) void attn_mfma(
    const __bf16* __restrict__ qkv, const __bf16* __restrict__ kx,
    const __bf16* __restrict__ vt, const float* __restrict__ obs,
    const float* __restrict__ Woq, const float* __restrict__ boq,
    const float* __restrict__ varb, const float* __restrict__ rtb,
    __bf16* __restrict__ aout)
{
    __shared__ __align__(16) __bf16 Ks[64][128];  // [m][128]: 8 content,4 obs,4 junk
    __shared__ __align__(16) __bf16 Vs[64][64];   // [d][m] swizzled
    __shared__ __align__(16) __bf16 Ps[64][64];   // [n][m] swizzled
    __shared__ float rts[96];

    const int tid = threadIdx.x;
    const int w = tid >> 6, lane = tid & 63;
    const int quad = lane >> 4, l16 = lane & 15;
    const int qt = blockIdx.x, bh = blockIdx.y;
    const int b = bh >> 3, h = bh & 7;
    const int n0 = qt * 64;

    if (tid < 95) rts[tid] = rtb[h * 95 + tid] * L2E;

    // Q fragments: wave w owns rows w*16..w*16+15
    const size_t qrow = (size_t)(b * NN + n0 + w * 16 + l16);
    bf16x8 aq[3];
    aq[0] = *(const bf16x8*)(qkv + qrow * 1536 + h * 64 + quad * 8);
    aq[1] = *(const bf16x8*)(qkv + qrow * 1536 + h * 64 + 32 + quad * 8);
    {   // inline oq: logical k 64..95 -> oq[0..15] then zeros; 0.25*log2e folded
        uint4 a2u = {0u, 0u, 0u, 0u};
        if (quad < 2) {
            float o0 = obs[qrow * 2], o1 = obs[qrow * 2 + 1];
            int f = h * 16 + quad * 8;
            const float sc = 0.25f * L2E;
            __bf16 tmp[8];
            #pragma unroll
            for (int j = 0; j < 8; j++)
                tmp[j] = (__bf16)(sc * (o0 * Woq[f + j] + o1 * Woq[128 + f + j]
                                        + boq[f + j]));
            a2u = *(uint4*)tmp;
        }
        aq[2] = *(bf16x8*)&a2u;
    }

    float vb0[4], vb1[4];
    #pragma unroll
    for (int r = 0; r < 4; r++) {
        int rm = (w * 16 + quad * 4 + r) & 31;
        vb0[r] = varb[h * 1024 + rm * 32 + l16] * L2E;
        vb1[r] = varb[h * 1024 + rm * 32 + 16 + l16] * L2E;
    }
    const int tn = 2 * qt + (w >> 1);

    // K staging: thread supplies phys chunk (tid&15) of rows (tid>>4)+16i;
    // logical chunk ck = (tid&15) ^ (row&7). Single uniform base array.
    const int ck = (tid & 15) ^ ((tid >> 4) & 7);
    const __bf16* kbase = kx + (size_t)bh * NN * 96 + ck * 8;
    // V staging: phys chunk (tid&7) of rows (tid>>3)+32i.
    const int cv = (tid & 7) ^ ((tid >> 3) & 7);
    const __bf16* vbase = vt + (size_t)bh * 64 * 1536 + cv * 8;

    f32x4 zero4 = {0.f, 0.f, 0.f, 0.f};
    f32x4 o[4];
    float lpart[4];
    #pragma unroll
    for (int i = 0; i < 4; i++) { o[i] = zero4; lpart[i] = 0.f; }

    char* ldsK = (char*)Ks;
    char* ldsV = (char*)Vs;

    for (int mt = 0; mt < 24; mt++) {
        const int m0 = mt * 64;
        __syncthreads();
        #pragma unroll
        for (int i = 0; i < 4; i++) {
            int row = i * 16 + (tid >> 4);
            GLOAD_LDS(kbase + (size_t)(m0 + row) * 96, ldsK + i * 4096 + tid * 16);
        }
        #pragma unroll
        for (int i = 0; i < 2; i++) {
            int row = i * 32 + (tid >> 3);
            GLOAD_LDS(vbase + (size_t)row * 1536 + m0, ldsV + i * 4096 + tid * 16);
        }
        __syncthreads();

        // ---- QK over K=96 ----
        f32x4 sc[4];
        #pragma unroll
        for (int ct = 0; ct < 4; ct++) {
            f32x4 d = zero4;
            int row = ct * 16 + l16;
            #pragma unroll
            for (int ks = 0; ks < 3; ks++) {
                bf16x8 bf = *(const bf16x8*)((const char*)Ks + row * 256
                                + (((ks * 4 + quad) ^ (row & 7)) * 16));
                d = __builtin_amdgcn_mfma_f32_16x16x32_bf16(aq[ks], bf, d, 0, 0, 0);
            }
            sc[ct] = d;
        }
        // ---- biases + exp2 (log2e pre-folded everywhere) ----
        float tb0 = rts[tn - 2 * mt + 47];
        float tb1 = rts[tn - 2 * mt + 46];
        #pragma unroll
        for (int ct = 0; ct < 4; ct++) {
            float tb = (ct & 2) ? tb1 : tb0;
            #pragma unroll
            for (int r = 0; r < 4; r++) {
                float s = sc[ct][r] + tb + ((ct & 1) ? vb1[r] : vb0[r]);
                float p = exp2f(s);
                lpart[r] += p;
                int rowp = w * 16 + quad * 4 + r;
                int pc = ((ct * 2) + (l16 >> 3)) ^ (rowp & 7);
                Ps[rowp][pc * 8 + (l16 & 7)] = (__bf16)p;
            }
        }
        // ---- PV (P rows wave-private: no barrier) ----
        #pragma unroll
        for (int ks = 0; ks < 2; ks++) {
            int rowr = w * 16 + l16;
            bf16x8 pf = *(const bf16x8*)&Ps[rowr][((ks * 4 + quad) ^ (l16 & 7)) * 8];
            #pragma unroll
            for (int dt = 0; dt < 4; dt++) {
                int rw = dt * 16 + l16;
                bf16x8 vf = *(const bf16x8*)((const char*)Vs + rw * 128
                                + (((ks * 4 + quad) ^ (rw & 7)) * 16));
                o[dt] = __builtin_amdgcn_mfma_f32_16x16x32_bf16(pf, vf, o[dt], 0, 0, 0);
            }
        }
    }

    // final l reduction + epilogue: aout[b][n][h*64+d]
    #pragma unroll
    for (int r = 0; r < 4; r++) {
        float l = lpart[r];
        l += __shfl_xor(l, 1);
        l += __shfl_xor(l, 2);
        l += __shfl_xor(l, 4);
        l += __shfl_xor(l, 8);
        float inv = 1.0f / l;
        int n = n0 + w * 16 + quad * 4 + r;
        size_t base = ((size_t)b * NN + n) * 512 + h * 64 + l16;
        #pragma unroll
        for (int dt = 0; dt < 4; dt++)
            aout[base + dt * 16] = (__bf16)(o[dt][r] * inv);
    }
}

extern "C" void kernel_launch(void* const* d_in, const int* in_sizes, int n_in,
                              void* d_out, int out_size, void* d_ws, size_t ws_size,
                              hipStream_t stream)
{
    const float* h_   = (const float*)d_in[0];
    const float* obs  = (const float*)d_in[1];
    const float* Wq   = (const float*)d_in[2];
    const float* bq   = (const float*)d_in[3];
    const float* Wk   = (const float*)d_in[4];
    const float* bk   = (const float*)d_in[5];
    const float* Wv   = (const float*)d_in[6];
    const float* bv   = (const float*)d_in[7];
    const float* Wo   = (const float*)d_in[8];
    const float* bo   = (const float*)d_in[9];
    const float* Woq  = (const float*)d_in[10];
    const float* boq  = (const float*)d_in[11];
    const float* Wok  = (const float*)d_in[12];
    const float* bok  = (const float*)d_in[13];
    const float* varb = (const float*)d_in[14];
    const float* rtb  = (const float*)d_in[15];
    float* out = (float*)d_out;

    char* ws = (char*)d_ws;
    __bf16* h_bf    = (__bf16*)ws;                 ws += (size_t)NBN * 512 * 2;   // aliased by vt
    __bf16* qkv     = (__bf16*)ws;                 ws += (size_t)NBN * 1536 * 2;
    __bf16* kx      = (__bf16*)ws;                 ws += ((size_t)32 * NN * 96 + 64) * 2;
    __bf16* attnout = (__bf16*)ws;                 ws += (size_t)NBN * 512 * 2;
    __bf16* WcatT   = (__bf16*)ws;                 ws += (size_t)1536 * 512 * 2;
    __bf16* WoT     = (__bf16*)ws;                 ws += (size_t)512 * 512 * 2;
    float*  biascat = (float*)ws;                  ws += 1536 * 4;
    __bf16* vt      = h_bf;   // h_bf dead after QKV GEMM; kvprep runs after it

    prep<<<dim3(2176), dim3(256), 0, stream>>>(
        h_, obs, Wq, Wk, Wv, Wo, bq, bk, bv, Wok, bok,
        h_bf, WcatT, WoT, biascat, kx);
    gemm_mfma<128, true><<<dim3(12, 48), dim3(256), 0, stream>>>(
        h_bf, WcatT, biascat, nullptr, qkv, 1536);
    kvprep<<<dim3(24, 32), dim3(256), 0, stream>>>(qkv, kx, vt);
    attn_mfma<<<dim3(24, 32), dim3(256), 0, stream>>>(qkv, kx, vt, obs, Woq, boq,
                                                      varb, rtb, attnout);
    gemm_mfma<64, false><<<dim3(4, 96), dim3(256), 0, stream>>>(
        attnout, WoT, bo, out, nullptr, 512);
}